// Round 6
// baseline (529.028 us; speedup 1.0000x reference)
//
#include <hip/hip_runtime.h>
#include <hip/hip_bf16.h>

#define BS    128
#define HDIM  512
#define NNODE 1024
#define BN    64
#define TPB   4                  // n-tiles per block
#define NT    16                 // tiles per batch
#define NBLK  (BS*4)             // 512 blocks, each covers a 256-node quarter
#define NTHR  512                // 8 waves

typedef __bf16 bf16x8 __attribute__((ext_vector_type(8)));
typedef float  f32x4  __attribute__((ext_vector_type(4)));

__device__ __forceinline__ unsigned short f2bf(float x) {
    unsigned int u = __builtin_bit_cast(unsigned int, x);
    unsigned int r = (u + 0x7FFFu + ((u >> 16) & 1u)) >> 16;
    return (unsigned short)r;
}

__device__ __forceinline__ unsigned int cvt_pk_bf16(float lo, float hi) {
    unsigned int r;
    asm("v_cvt_pk_bf16_f32 %0, %1, %2" : "=v"(r) : "v"(lo), "v"(hi));
    return r;
}

__device__ __forceinline__ float tanh_fast(float x) {
    float e = __expf(2.0f * x);
    return 1.0f - 2.0f / (e + 1.0f);
}

// ---- kernel 1: cast W_ref (f32 [512][512]) -> bf16 ----
__global__ void k_cast_w(const float* __restrict__ W, unsigned short* __restrict__ Wb) {
    int i = (blockIdx.x * 256 + threadIdx.x) * 4;
    float4 v = *(const float4*)(W + i);
    ushort4 o;
    o.x = f2bf(v.x); o.y = f2bf(v.y); o.z = f2bf(v.z); o.w = f2bf(v.w);
    *(ushort4*)(Wb + i) = o;
}

// ---- kernel 2: u1b[b][o] = (q @ W_q^T + b_q + b_ref)[b][o]  (fp32, feeds tanh) ----
__global__ void k_u1(const float* __restrict__ q, const float* __restrict__ Wq,
                     const float* __restrict__ bq, const float* __restrict__ bref,
                     float* __restrict__ u1b) {
    __shared__ float ql[HDIM];
    int b = blockIdx.x, o = threadIdx.x;
    ql[o] = q[b * HDIM + o];
    __syncthreads();
    float acc = bq[o] + bref[o];   // b_ref belongs INSIDE tanh(u1+u2)
    const float* wr = Wq + (size_t)o * HDIM;
    #pragma unroll 4
    for (int h = 0; h < HDIM; h += 4) {
        float4 w = *(const float4*)(wr + h);
        acc += w.x * ql[h] + w.y * ql[h + 1] + w.z * ql[h + 2] + w.w * ql[h + 3];
    }
    u1b[b * HDIM + o] = acc;
}

// ---- kernel 3: main fused kernel ----
// 512 threads = 8 waves; wave w owns output rows [w*64, w*64+64): acc[4][4] = 64 AGPR.
// __launch_bounds__(512,2): arch-VGPR cap 128; 128+64 AGPR = 192 <= 256/wave at
// 2 waves/SIMD -> launch guaranteed (rounds 4/5 failed launch from AGPR overflow).
// Single static 64KB tile buffer. Tile t+1 loads issued BEFORE GEMM(t) (HBM latency
// hides under MFMA); commit after barB (all Bs reads done), overlapping wave0 softmax.
__launch_bounds__(NTHR, 2)
__global__ void k_main(const float* __restrict__ ref, const int* __restrict__ mask,
                       const float* __restrict__ v, const unsigned short* __restrict__ Wb,
                       const float* __restrict__ u1b,
                       float* __restrict__ stats, float* __restrict__ dts)
{
    __shared__ unsigned short Bs[BN * 512];   // [n][k] bf16, XOR-swizzled, 64 KB
    __shared__ float u1l[HDIM];
    __shared__ float vl[HDIM];
    __shared__ float sred[8 * BN];
    __shared__ float wts[BN];
    __shared__ int   maskl[TPB * BN];         // this block's 256 mask entries

    const int bid  = blockIdx.x;
    const int b    = bid >> 2;
    const int q4   = bid & 3;
    const int tid  = threadIdx.x;
    const int wave = tid >> 6;
    const int lane = tid & 63;
    const int cl   = lane & 15;
    const int gr   = lane >> 4;
    const int wo   = wave * 64;

    u1l[tid] = u1b[b * HDIM + tid];
    vl[tid]  = v[tid];
    if (tid < TPB * BN) maskl[tid] = mask[b * NNODE + q4 * (TPB * BN) + tid];

    // staging geometry: thread owns 16 h-rows x 4 n-cols of the 512h x 64n tile
    const int sn = (tid & 15) * 4;        // n base
    const int sh = (tid >> 4) * 16;       // h base (0..496)
    const float* refq = ref + (size_t)b * HDIM * NNODE + (size_t)sh * NNODE
                            + q4 * (TPB * BN) + sn;

    float4 G[16];
    auto stage_issue = [&](int t) {
        const float* p = refq + t * BN;
        #pragma unroll
        for (int j = 0; j < 16; j++)
            G[j] = *(const float4*)(p + (size_t)j * NNODE);
    };
    // swizzle: slot ^= (n ^ (n>>3)) & 7  — balanced on both ds_write and ds_read
    auto stage_commit = [&]() {
        #pragma unroll
        for (int c = 0; c < 4; c++) {
            const int nn = sn + c;
            const int swz = (nn ^ (nn >> 3)) & 7;
            unsigned int u[8];
            #pragma unroll
            for (int hp = 0; hp < 8; hp++)
                u[hp] = cvt_pk_bf16(((const float*)&G[2 * hp])[c],
                                    ((const float*)&G[2 * hp + 1])[c]);
            const int s0 = ((sh >> 3) + 0) ^ swz;
            const int s1 = ((sh >> 3) + 1) ^ swz;
            *(uint4*)&Bs[nn * 512 + s0 * 8] = make_uint4(u[0], u[1], u[2], u[3]);
            *(uint4*)&Bs[nn * 512 + s1 * 8] = make_uint4(u[4], u[5], u[6], u[7]);
        }
    };

    const unsigned short* wpa = Wb + (size_t)(wo + cl) * 512 + gr * 8;

    stage_issue(0);
    stage_commit();
    __syncthreads();

    for (int t = 0; t < TPB; t++) {
        if (t + 1 < TPB) stage_issue(t + 1);   // HBM loads in flight across GEMM

        f32x4 acc[4][4];
        #pragma unroll
        for (int m = 0; m < 4; m++)
            #pragma unroll
            for (int nf = 0; nf < 4; nf++)
                acc[m][nf] = (f32x4){0.f, 0.f, 0.f, 0.f};

        bf16x8 A0[4], A1[4], B[4];
        auto lda = [&](bf16x8 (&dst)[4], int kks) {
            #pragma unroll
            for (int m = 0; m < 4; m++)
                dst[m] = *(const bf16x8*)(wpa + (size_t)m * 16 * 512 + kks * 32);
        };
        auto ldb = [&](int kks) {
            #pragma unroll
            for (int nf = 0; nf < 4; nf++) {
                int n = nf * 16 + cl;
                int slot = ((kks << 2) + gr) ^ ((n ^ (n >> 3)) & 7);
                B[nf] = *(const bf16x8*)&Bs[n * 512 + slot * 8];
            }
        };
        auto mm = [&](bf16x8 (&Aa)[4]) {
            #pragma unroll
            for (int m = 0; m < 4; m++)
                #pragma unroll
                for (int nf = 0; nf < 4; nf++)
                    acc[m][nf] = __builtin_amdgcn_mfma_f32_16x16x32_bf16(Aa[m], B[nf], acc[m][nf], 0, 0, 0);
        };

        lda(A0, 0);
        #pragma unroll
        for (int kk = 0; kk < 16; kk += 2) {
            lda(A1, kk + 1);
            ldb(kk);
            mm(A0);
            if (kk + 2 < 16) lda(A0, kk + 2);
            ldb(kk + 1);
            mm(A1);
        }

        // ---- scores: sp[nf] = sum over this wave's 64 rows of v[o]*tanh(u1[o]+u2) ----
        float sp[4] = {0.f, 0.f, 0.f, 0.f};
        #pragma unroll
        for (int m = 0; m < 4; m++) {
            #pragma unroll
            for (int r = 0; r < 4; r++) {
                int o = wo + m * 16 + gr * 4 + r;
                float uo = u1l[o];
                float vv = vl[o];
                #pragma unroll
                for (int nf = 0; nf < 4; nf++)
                    sp[nf] += vv * tanh_fast(uo + acc[m][nf][r]);
            }
        }
        #pragma unroll
        for (int nf = 0; nf < 4; nf++) {
            sp[nf] += __shfl_xor(sp[nf], 16);
            sp[nf] += __shfl_xor(sp[nf], 32);
        }
        if (lane < 16) {
            #pragma unroll
            for (int nf = 0; nf < 4; nf++)
                sred[wave * BN + nf * 16 + lane] = sp[nf];
        }
        __syncthreads();   // barB: all GEMM reads of Bs done + sred ready

        if (t + 1 < TPB) stage_commit();   // overwrite Bs with tile t+1 (race-free)

        if (wave == 0) {
            float u = 0.f;
            #pragma unroll
            for (int w = 0; w < 8; w++) u += sred[w * BN + lane];
            u -= 1e8f * (float)maskl[t * BN + lane];
            float mx = u;
            #pragma unroll
            for (int off = 1; off < 64; off <<= 1) mx = fmaxf(mx, __shfl_xor(mx, off));
            float wv = __expf(u - mx);
            float s = wv;
            #pragma unroll
            for (int off = 1; off < 64; off <<= 1) s += __shfl_xor(s, off);
            wts[lane] = wv;
            if (lane == 0) {
                int gslot = bid * TPB + t;
                stats[gslot * 2]     = mx;
                stats[gslot * 2 + 1] = s;
            }
        }
        __syncthreads();   // barC: wts ready + Bs(t+1) committed

        // ---- d_t[o] = sum_n acc[o][n] * w_n ----
        float wc[4];
        #pragma unroll
        for (int nf = 0; nf < 4; nf++) wc[nf] = wts[nf * 16 + cl];
        float* dout = dts + (size_t)(bid * TPB + t) * HDIM;
        #pragma unroll
        for (int m = 0; m < 4; m++) {
            #pragma unroll
            for (int r = 0; r < 4; r++) {
                float d = acc[m][0][r] * wc[0] + acc[m][1][r] * wc[1]
                        + acc[m][2][r] * wc[2] + acc[m][3][r] * wc[3];
                d += __shfl_xor(d, 1);
                d += __shfl_xor(d, 2);
                d += __shfl_xor(d, 4);
                d += __shfl_xor(d, 8);
                if (cl == 0) dout[wo + m * 16 + gr * 4 + r] = d;
            }
        }
    }
}

// ---- kernel 4: combine 16 tiles per batch ----
__global__ void k_comb(const float* __restrict__ stats, const float* __restrict__ dts,
                       const float* __restrict__ bref, float* __restrict__ out) {
    __shared__ float sm[NT], sl[NT];
    int b = blockIdx.x, tid = threadIdx.x;
    if (tid < NT) {
        sm[tid] = stats[(b * NT + tid) * 2];
        sl[tid] = stats[(b * NT + tid) * 2 + 1];
    }
    __syncthreads();
    float m = -3.4e38f;
    #pragma unroll
    for (int t = 0; t < NT; t++) m = fmaxf(m, sm[t]);
    float sc[NT];
    float L = 0.f;
    #pragma unroll
    for (int t = 0; t < NT; t++) { sc[t] = __expf(sm[t] - m); L += sc[t] * sl[t]; }
    float inv = 1.0f / L;
    float acc = 0.f;
    #pragma unroll
    for (int t = 0; t < NT; t++)
        acc += sc[t] * dts[((size_t)b * NT + t) * HDIM + tid];
    out[b * HDIM + tid] = acc * inv + bref[tid];
}

extern "C" void kernel_launch(void* const* d_in, const int* in_sizes, int n_in,
                              void* d_out, int out_size, void* d_ws, size_t ws_size,
                              hipStream_t stream) {
    const float* q    = (const float*)d_in[0];
    const float* ref  = (const float*)d_in[1];
    const int*   mask = (const int*)d_in[2];
    const float* v    = (const float*)d_in[3];
    const float* Wq   = (const float*)d_in[4];
    const float* bq   = (const float*)d_in[5];
    const float* Wref = (const float*)d_in[6];
    const float* bref = (const float*)d_in[7];
    float* out = (float*)d_out;

    char* ws = (char*)d_ws;
    unsigned short* wbf = (unsigned short*)ws;                 // 524288 B
    float* u1b   = (float*)(ws + 524288);                      // 262144 B
    float* stats = (float*)(ws + 524288 + 262144);             // 16384 B
    float* dts   = (float*)(ws + 524288 + 262144 + 16384);     // 4 MB

    k_cast_w<<<256, 256, 0, stream>>>(Wref, wbf);
    k_u1<<<BS, HDIM, 0, stream>>>(q, Wq, bq, bref, u1b);
    k_main<<<NBLK, NTHR, 0, stream>>>(ref, mask, v, wbf, u1b, stats, dts);
    k_comb<<<BS, HDIM, 0, stream>>>(stats, dts, bref, out);
}

// Round 7
// 417.203 us; speedup vs baseline: 1.2680x; 1.2680x over previous
//
#include <hip/hip_runtime.h>
#include <hip/hip_bf16.h>

#define BS    128
#define HDIM  512
#define NNODE 1024
#define BN    64
#define TPB   4                  // n-tiles per block
#define NT    16                 // tiles per batch
#define NBLK  (BS*4)             // 512 blocks, each covers a 256-node quarter
#define NTHR  512                // 8 waves

typedef __bf16 bf16x8 __attribute__((ext_vector_type(8)));
typedef float  f32x4  __attribute__((ext_vector_type(4)));

__device__ __forceinline__ unsigned short f2bf(float x) {
    unsigned int u = __builtin_bit_cast(unsigned int, x);
    unsigned int r = (u + 0x7FFFu + ((u >> 16) & 1u)) >> 16;
    return (unsigned short)r;
}

__device__ __forceinline__ unsigned int cvt_pk_bf16(float lo, float hi) {
    unsigned int r;
    asm("v_cvt_pk_bf16_f32 %0, %1, %2" : "=v"(r) : "v"(lo), "v"(hi));
    return r;
}

__device__ __forceinline__ float tanh_fast(float x) {
    float e = __expf(2.0f * x);
    return 1.0f - 2.0f / (e + 1.0f);
}

// ---- kernel 1: cast W_ref (f32 [512][512]) -> bf16 ----
__global__ void k_cast_w(const float* __restrict__ W, unsigned short* __restrict__ Wb) {
    int i = (blockIdx.x * 256 + threadIdx.x) * 4;
    float4 v = *(const float4*)(W + i);
    ushort4 o;
    o.x = f2bf(v.x); o.y = f2bf(v.y); o.z = f2bf(v.z); o.w = f2bf(v.w);
    *(ushort4*)(Wb + i) = o;
}

// ---- kernel 2: u1b[b][o] = (q @ W_q^T + b_q + b_ref)[b][o]  (fp32, feeds tanh) ----
__global__ void k_u1(const float* __restrict__ q, const float* __restrict__ Wq,
                     const float* __restrict__ bq, const float* __restrict__ bref,
                     float* __restrict__ u1b) {
    __shared__ float ql[HDIM];
    int b = blockIdx.x, o = threadIdx.x;
    ql[o] = q[b * HDIM + o];
    __syncthreads();
    float acc = bq[o] + bref[o];   // b_ref belongs INSIDE tanh(u1+u2)
    const float* wr = Wq + (size_t)o * HDIM;
    #pragma unroll 4
    for (int h = 0; h < HDIM; h += 4) {
        float4 w = *(const float4*)(wr + h);
        acc += w.x * ql[h] + w.y * ql[h + 1] + w.z * ql[h + 2] + w.w * ql[h + 3];
    }
    u1b[b * HDIM + o] = acc;
}

// ---- kernel 3: main fused kernel ----
// 512 thr = 8 waves; wave owns rows [w*64, w*64+64): acc[4][4] = 64 AGPR.
// (512,2): arch cap 128; 128+64 <= 192 -> guaranteed launch, 1 block/CU.
// Double-buffered 2x64KB LDS tile. Tile t+1 staged in TWO halves (G[8]=32 VGPR
// live range only spans half the GEMM): issue h1 -> GEMM k0..7 -> commit h1 +
// issue h2 -> GEMM k8..15 -> commit h2. Commits write buffer `nxt` while GEMM
// reads `cur` (no race); barC orders nxt before GEMM(t+1).
__launch_bounds__(NTHR, 2)
__global__ void k_main(const float* __restrict__ ref, const int* __restrict__ mask,
                       const float* __restrict__ v, const unsigned short* __restrict__ Wb,
                       const float* __restrict__ u1b,
                       float* __restrict__ stats, float* __restrict__ dts)
{
    __shared__ unsigned short Bs[2][BN * 512];  // 2 x 64 KB, XOR-swizzled [n][k]
    __shared__ float u1l[HDIM];
    __shared__ float vl[HDIM];
    __shared__ float sred[8 * BN];
    __shared__ float wts[BN];
    __shared__ int   maskl[TPB * BN];

    const int bid  = blockIdx.x;
    const int b    = bid >> 2;
    const int q4   = bid & 3;
    const int tid  = threadIdx.x;
    const int wave = tid >> 6;
    const int lane = tid & 63;
    const int cl   = lane & 15;
    const int gr   = lane >> 4;
    const int wo   = wave * 64;

    u1l[tid] = u1b[b * HDIM + tid];
    vl[tid]  = v[tid];
    if (tid < TPB * BN) maskl[tid] = mask[b * NNODE + q4 * (TPB * BN) + tid];

    // staging geometry: thread owns 16 h-rows x 4 n-cols (in two halves of 8 rows)
    const int sn = (tid & 15) * 4;        // n base
    const int sh = (tid >> 4) * 16;       // h base (0..496)
    const float* refq = ref + (size_t)b * HDIM * NNODE + (size_t)sh * NNODE
                            + q4 * (TPB * BN) + sn;

    float4 G[8];
    auto issue_half = [&](int t, int half) {
        const float* p = refq + t * BN + (size_t)(half * 8) * NNODE;
        #pragma unroll
        for (int j = 0; j < 8; j++)
            G[j] = *(const float4*)(p + (size_t)j * NNODE);
    };
    auto commit_half = [&](unsigned short* Bsb, int half) {
        #pragma unroll
        for (int c = 0; c < 4; c++) {
            const int nn = sn + c;
            const int swz = (nn ^ (nn >> 3)) & 7;
            unsigned int u0 = cvt_pk_bf16(((const float*)&G[0])[c], ((const float*)&G[1])[c]);
            unsigned int u1 = cvt_pk_bf16(((const float*)&G[2])[c], ((const float*)&G[3])[c]);
            unsigned int u2 = cvt_pk_bf16(((const float*)&G[4])[c], ((const float*)&G[5])[c]);
            unsigned int u3 = cvt_pk_bf16(((const float*)&G[6])[c], ((const float*)&G[7])[c]);
            const int s0 = ((sh >> 3) + half) ^ swz;
            *(uint4*)&Bs[0][0 + (size_t)((Bsb - &Bs[0][0])) + nn * 512 + s0 * 8] =
                make_uint4(u0, u1, u2, u3);
        }
    };

    const unsigned short* wpa = Wb + (size_t)(wo + cl) * 512 + gr * 8;

    // prologue: stage tile 0 into Bs[0]
    issue_half(0, 0);
    commit_half(&Bs[0][0], 0);
    issue_half(0, 1);
    commit_half(&Bs[0][0], 1);
    __syncthreads();

    for (int t = 0; t < TPB; t++) {
        const unsigned short* cur = &Bs[t & 1][0];
        unsigned short*       nxt = &Bs[(t + 1) & 1][0];
        const bool more = (t + 1 < TPB);

        if (more) issue_half(t + 1, 0);

        f32x4 acc[4][4];
        #pragma unroll
        for (int m = 0; m < 4; m++)
            #pragma unroll
            for (int nf = 0; nf < 4; nf++)
                acc[m][nf] = (f32x4){0.f, 0.f, 0.f, 0.f};

        bf16x8 A0[4], A1[4], B[4];
        auto lda = [&](bf16x8 (&dst)[4], int kks) {
            #pragma unroll
            for (int m = 0; m < 4; m++)
                dst[m] = *(const bf16x8*)(wpa + (size_t)m * 16 * 512 + kks * 32);
        };
        auto ldb = [&](int kks) {
            #pragma unroll
            for (int nf = 0; nf < 4; nf++) {
                int n = nf * 16 + cl;
                int slot = ((kks << 2) + gr) ^ ((n ^ (n >> 3)) & 7);
                B[nf] = *(const bf16x8*)&cur[n * 512 + slot * 8];
            }
        };
        auto mm = [&](bf16x8 (&Aa)[4]) {
            #pragma unroll
            for (int m = 0; m < 4; m++)
                #pragma unroll
                for (int nf = 0; nf < 4; nf++)
                    acc[m][nf] = __builtin_amdgcn_mfma_f32_16x16x32_bf16(Aa[m], B[nf], acc[m][nf], 0, 0, 0);
        };

        lda(A0, 0);
        #pragma unroll
        for (int kk = 0; kk < 16; kk += 2) {
            if (kk == 8 && more) {
                commit_half(nxt, 0);   // waits half1 loads via reg deps
                issue_half(t + 1, 1);  // anti-dep on G keeps ordering
            }
            lda(A1, kk + 1);
            ldb(kk);
            mm(A0);
            if (kk + 2 < 16) lda(A0, kk + 2);
            ldb(kk + 1);
            mm(A1);
        }
        if (more) commit_half(nxt, 1);

        // ---- scores: sp[nf] = sum over this wave's 64 rows of v[o]*tanh(u1[o]+u2) ----
        float sp[4] = {0.f, 0.f, 0.f, 0.f};
        #pragma unroll
        for (int m = 0; m < 4; m++) {
            #pragma unroll
            for (int r = 0; r < 4; r++) {
                int o = wo + m * 16 + gr * 4 + r;
                float uo = u1l[o];
                float vv = vl[o];
                #pragma unroll
                for (int nf = 0; nf < 4; nf++)
                    sp[nf] += vv * tanh_fast(uo + acc[m][nf][r]);
            }
        }
        #pragma unroll
        for (int nf = 0; nf < 4; nf++) {
            sp[nf] += __shfl_xor(sp[nf], 16);
            sp[nf] += __shfl_xor(sp[nf], 32);
        }
        if (lane < 16) {
            #pragma unroll
            for (int nf = 0; nf < 4; nf++)
                sred[wave * BN + nf * 16 + lane] = sp[nf];
        }
        __syncthreads();   // barB: sred ready

        if (wave == 0) {
            float u = 0.f;
            #pragma unroll
            for (int w = 0; w < 8; w++) u += sred[w * BN + lane];
            u -= 1e8f * (float)maskl[t * BN + lane];
            float mx = u;
            #pragma unroll
            for (int off = 1; off < 64; off <<= 1) mx = fmaxf(mx, __shfl_xor(mx, off));
            float wv = __expf(u - mx);
            float s = wv;
            #pragma unroll
            for (int off = 1; off < 64; off <<= 1) s += __shfl_xor(s, off);
            wts[lane] = wv;
            if (lane == 0) {
                int gslot = bid * TPB + t;
                stats[gslot * 2]     = mx;
                stats[gslot * 2 + 1] = s;
            }
        }
        __syncthreads();   // barC: wts ready + nxt fully committed for GEMM(t+1)

        // ---- d_t[o] = sum_n acc[o][n] * w_n ----
        float wc[4];
        #pragma unroll
        for (int nf = 0; nf < 4; nf++) wc[nf] = wts[nf * 16 + cl];
        float* dout = dts + (size_t)(bid * TPB + t) * HDIM;
        #pragma unroll
        for (int m = 0; m < 4; m++) {
            #pragma unroll
            for (int r = 0; r < 4; r++) {
                float d = acc[m][0][r] * wc[0] + acc[m][1][r] * wc[1]
                        + acc[m][2][r] * wc[2] + acc[m][3][r] * wc[3];
                d += __shfl_xor(d, 1);
                d += __shfl_xor(d, 2);
                d += __shfl_xor(d, 4);
                d += __shfl_xor(d, 8);
                if (cl == 0) dout[wo + m * 16 + gr * 4 + r] = d;
            }
        }
    }
}

// ---- kernel 4: combine 16 tiles per batch ----
__global__ void k_comb(const float* __restrict__ stats, const float* __restrict__ dts,
                       const float* __restrict__ bref, float* __restrict__ out) {
    __shared__ float sm[NT], sl[NT];
    int b = blockIdx.x, tid = threadIdx.x;
    if (tid < NT) {
        sm[tid] = stats[(b * NT + tid) * 2];
        sl[tid] = stats[(b * NT + tid) * 2 + 1];
    }
    __syncthreads();
    float m = -3.4e38f;
    #pragma unroll
    for (int t = 0; t < NT; t++) m = fmaxf(m, sm[t]);
    float sc[NT];
    float L = 0.f;
    #pragma unroll
    for (int t = 0; t < NT; t++) { sc[t] = __expf(sm[t] - m); L += sc[t] * sl[t]; }
    float inv = 1.0f / L;
    float acc = 0.f;
    #pragma unroll
    for (int t = 0; t < NT; t++)
        acc += sc[t] * dts[((size_t)b * NT + t) * HDIM + tid];
    out[b * HDIM + tid] = acc * inv + bref[tid];
}

extern "C" void kernel_launch(void* const* d_in, const int* in_sizes, int n_in,
                              void* d_out, int out_size, void* d_ws, size_t ws_size,
                              hipStream_t stream) {
    const float* q    = (const float*)d_in[0];
    const float* ref  = (const float*)d_in[1];
    const int*   mask = (const int*)d_in[2];
    const float* v    = (const float*)d_in[3];
    const float* Wq   = (const float*)d_in[4];
    const float* bq   = (const float*)d_in[5];
    const float* Wref = (const float*)d_in[6];
    const float* bref = (const float*)d_in[7];
    float* out = (float*)d_out;

    char* ws = (char*)d_ws;
    unsigned short* wbf = (unsigned short*)ws;                 // 524288 B
    float* u1b   = (float*)(ws + 524288);                      // 262144 B
    float* stats = (float*)(ws + 524288 + 262144);             // 16384 B
    float* dts   = (float*)(ws + 524288 + 262144 + 16384);     // 4 MB

    k_cast_w<<<256, 256, 0, stream>>>(Wref, wbf);
    k_u1<<<BS, HDIM, 0, stream>>>(q, Wq, bq, bref, u1b);
    k_main<<<NBLK, NTHR, 0, stream>>>(ref, mask, v, wbf, u1b, stats, dts);
    k_comb<<<BS, HDIM, 0, stream>>>(stats, dts, bref, out);
}